// Round 13
// baseline (358.924 us; speedup 1.0000x reference)
//
#include <hip/hip_runtime.h>

// ---------------------------------------------------------------------------
// MultiheadAttention: T=1024, B=8, E=1024, H=16, HD=64, SCALE=0.125
// R18: fold V into the verified 8-phase 256^2 GEMM (R17 passed byte-exact).
//     k_gemm_qk -> k_gemm_qkv: N 2048->3072, grid (12,32)=384 blocks
//     (384%8==0 bijective XCD swizzle, chunk 48). Eliminates k_gemm_v's
//     dispatch + gap at the cost of a 1.5-round tail. V epilogue at 256^2:
//     4 quarters of 64 n-cols; per quarter the 2 owning waves (wid&3==qn)
//     write a [256][72] LDS tile (reuses the 128KB smem post-loop), then
//     wave=b lane=d threads emit 64B-contiguous Vt stores (2 lanes/dword =
//     conflict-free; t0g%32==0 -> 16B-aligned uint4). Main loop, k_attn
//     (R12 verbatim, knife-edge), prep, out: byte-identical to R17.
// ---------------------------------------------------------------------------

typedef __bf16 bf16x8 __attribute__((ext_vector_type(8)));
typedef float f32x4 __attribute__((ext_vector_type(4)));

#define LOG2E 1.4426950408889634f
#define QSCALE 0.18033688011112042f  // 0.125 * LOG2E

// round-to-nearest-even (one-time prep kernels)
static __device__ __forceinline__ unsigned short f2bf_rn(float f) {
  union { float f; unsigned u; } x;
  x.f = f;
  unsigned r = (x.u + 0x7fffu + ((x.u >> 16) & 1u)) >> 16;
  return (unsigned short)r;
}
// round-half-up (hot paths: 2 VALU ops)
static __device__ __forceinline__ unsigned short f2bf(float f) {
  union { float f; unsigned u; } x;
  x.f = f;
  return (unsigned short)((x.u + 0x8000u) >> 16);
}

static __device__ __forceinline__ void async_cp16(const void* g, void* l) {
  __builtin_amdgcn_global_load_lds((__attribute__((address_space(1))) void*)g,
                                   (__attribute__((address_space(3))) void*)l,
                                   16, 0, 0);
}

// ---------------- fused prep: biasT | transw4 | cvt | mask ----------------
// grid: [0,1024) biasT  [1024,5120) transw4  [5120,13312) cvt  [13312,13344) mask
__global__ __launch_bounds__(256, 2) void k_prep(
    const float* __restrict__ query, const int* __restrict__ mask,
    const float* __restrict__ bias,
    const float* __restrict__ wq, const float* __restrict__ wk,
    const float* __restrict__ wv, const float* __restrict__ wo,
    unsigned short* __restrict__ Abuf, float* __restrict__ Mfg,
    unsigned short* __restrict__ WqkvT, unsigned short* __restrict__ WoT,
    unsigned short* __restrict__ B2) {
  __shared__ char shraw[128 * 132 * 2];  // 33792 B (biasT tile; transw reuses)
  const int bid = blockIdx.x;
  const int tid = threadIdx.x;

  if (bid < 1024) {
    // ---- biasT: fragment-layout bf16, log2 domain ----
    unsigned short* tile = (unsigned short*)shraw;
    const int ss = bid & 7, tt = (bid >> 3) & 7, h = bid >> 6;
    const float* src = bias + ((long)h * 1024 + tt * 128) * 1024 + ss * 128;
#pragma unroll
    for (int c = 0; c < 16; ++c) {
      int flat = c * 256 + tid;
      int row = flat >> 5, col = (flat & 31) << 2;
      float4 v = *(const float4*)(src + (long)row * 1024 + col);
      unsigned short* t4 = &tile[row * 132 + col];
      t4[0] = f2bf_rn(v.x * LOG2E); t4[1] = f2bf_rn(v.y * LOG2E);
      t4[2] = f2bf_rn(v.z * LOG2E); t4[3] = f2bf_rn(v.w * LOG2E);
    }
    __syncthreads();
    const int wid = tid >> 6, lane = tid & 63, lanelo = lane & 15, quad = lane >> 4;
    unsigned short outv[64];
#pragma unroll
    for (int mi = 0; mi < 2; ++mi)
#pragma unroll
      for (int nj = 0; nj < 8; ++nj)
#pragma unroll
        for (int r = 0; r < 4; ++r)
          outv[mi * 32 + nj * 4 + r] =
              tile[(wid * 32 + mi * 16 + quad * 4 + r) * 132 + nj * 16 + lanelo];
    unsigned short* dst = B2 + ((((long)(h * 8 + tt) * 8 + ss) * 256 + tid) << 6);
#pragma unroll
    for (int i = 0; i < 8; ++i) ((uint4*)dst)[i] = ((const uint4*)outv)[i];
  } else if (bid < 5120) {
    // ---- transw4: dst[e][d] = f2bf(src[d][e]) ----
    float (*tile)[33] = (float(*)[33])shraw;
    const int f = bid - 1024;
    const int bx = (f & 31) << 5;
    const int by = ((f >> 5) & 31) << 5;
    const int z = f >> 10;
    const float* src = (z == 0) ? wq : (z == 1) ? wk : (z == 2) ? wv : wo;
    unsigned short* dst = (z < 3) ? WqkvT + (size_t)z * 1024 * 1024 : WoT;
    const int tx = tid & 31, ty = tid >> 5;
#pragma unroll
    for (int i = 0; i < 32; i += 8)
      tile[ty + i][tx] = src[(size_t)(by + ty + i) * 1024 + bx + tx];
    __syncthreads();
#pragma unroll
    for (int i = 0; i < 32; i += 8)
      dst[(size_t)(bx + ty + i) * 1024 + by + tx] = f2bf_rn(tile[tx][ty + i]);
  } else if (bid < 13312) {
    // ---- cvt: query fp32 -> bf16 ----
    const int idx = (bid - 5120) * 256 + tid;
    const float4 f = ((const float4*)query)[idx];
    unsigned lo = (unsigned)f2bf_rn(f.x) | ((unsigned)f2bf_rn(f.y) << 16);
    unsigned hi = (unsigned)f2bf_rn(f.z) | ((unsigned)f2bf_rn(f.w) << 16);
    uint2 v; v.x = lo; v.y = hi;
    *(uint2*)(Abuf + (size_t)idx * 4) = v;
  } else {
    // ---- mask -> additive float ----
    const int i = (bid - 13312) * 256 + tid;  // 8192 total
    Mfg[i] = mask[i] ? -1e30f : 0.f;
  }
}

// ===================== 8-phase 256x256 QKV GEMM ============================
// C[0:8192, 0:3072] of Abuf x WqkvT^T; bx 0-3 -> Qh, 4-7 -> Kh, 8-11 -> Vt.
// LDS slots (16KB = 8192 shorts each): per buffer q (=tile%2):
//   A-kk0 = q*4+0, A-kk1 = q*4+1, B-kk0 = q*4+2, B-kk1 = q*4+3.
// Slot layout: lds_line (64 shorts) = 2 source rows; 16B chunk at pos
//   ((row&1)*4 + c) ^ (lds_line&7), c = k-chunk (8 shorts) within kk-half.
__global__ __launch_bounds__(512, 2) void k_gemm_qkv(
    const unsigned short* __restrict__ A, const unsigned short* __restrict__ Bt,
    unsigned short* __restrict__ Qh, unsigned short* __restrict__ Kh,
    unsigned short* __restrict__ Vt) {
  __shared__ unsigned short smem[65536];  // 128 KB

  const int tid = threadIdx.x;
  const int wid = tid >> 6;
  const int lane = tid & 63;
  const int lanelo = lane & 15;
  const int quad = lane >> 4;
  const int wm = (wid >> 2) << 7;  // 0 / 128
  const int wn = (wid & 3) << 6;   // 0 / 64 / 128 / 192
  const int K = 1024;

  // XCD swizzle: grid (12,32) = 384 blocks, chunk 48/XCD
  const int flat = blockIdx.y * 12 + blockIdx.x;
  const int swz = (flat & 7) * 48 + (flat >> 3);  // bijective (384%8==0)
  const int bx = swz % 12, by = swz / 12;
  const long m0 = (long)by * 256;
  const long n0 = (long)bx * 256;

  // staging geometry: thread stages 16B chunks L = tid (rows 0-127 half)
  // and L = tid+512 (rows 128-255). Inverse of the LDS interleave:
  const int x_ = (tid & 7) ^ ((tid >> 3) & 7);
  const int row_s = ((tid >> 3) << 1) + (x_ >> 2);
  const int col_s = (x_ & 3) << 3;
  const unsigned short* gA = A + (m0 + row_s) * K + col_s;
  const unsigned short* gB = Bt + (n0 + row_s) * K + col_s;

#define STG(slot, gp, kc)                                        \
  do {                                                           \
    const unsigned short* _g = (gp) + (kc);                      \
    char* _l = (char*)smem + ((slot) << 14) + (wid << 10);       \
    async_cp16(_g, _l);                                          \
    async_cp16(_g + 128 * 1024, _l + 8192);                      \
  } while (0)

  // ds_read offsets (shorts): line = base_line + 8*frag; pos per-lane const
  const int lhalf = lanelo >> 1;
  const int posa = ((((lanelo & 1) << 2) + quad) ^ lhalf) << 3;
  const int aoff = ((wm >> 1) + lhalf) * 64 + posa;
  const int boff = ((wn >> 1) + lhalf) * 64 + posa;

  bf16x8 a[4], b[4];
#define LDA4(slot, mb)                                                        \
  do {                                                                        \
    a[0] = *(const bf16x8*)(smem + (slot) * 8192 + aoff + ((mb) + 0) * 512);  \
    a[1] = *(const bf16x8*)(smem + (slot) * 8192 + aoff + ((mb) + 1) * 512);  \
    a[2] = *(const bf16x8*)(smem + (slot) * 8192 + aoff + ((mb) + 2) * 512);  \
    a[3] = *(const bf16x8*)(smem + (slot) * 8192 + aoff + ((mb) + 3) * 512);  \
  } while (0)
#define LDB4(slot)                                                            \
  do {                                                                        \
    b[0] = *(const bf16x8*)(smem + (slot) * 8192 + boff + 0 * 512);           \
    b[1] = *(const bf16x8*)(smem + (slot) * 8192 + boff + 1 * 512);           \
    b[2] = *(const bf16x8*)(smem + (slot) * 8192 + boff + 2 * 512);           \
    b[3] = *(const bf16x8*)(smem + (slot) * 8192 + boff + 3 * 512);           \
  } while (0)

  f32x4 acc[8][4];
  const f32x4 z4 = {0.f, 0.f, 0.f, 0.f};
#pragma unroll
  for (int i = 0; i < 8; ++i)
#pragma unroll
    for (int j = 0; j < 4; ++j) acc[i][j] = z4;

#define MMA16(mb)                                                             \
  do {                                                                        \
    __builtin_amdgcn_s_setprio(1);                                            \
    _Pragma("unroll") for (int x = 0; x < 4; ++x)                             \
        _Pragma("unroll") for (int y = 0; y < 4; ++y)                         \
        acc[(mb) + x][y] = __builtin_amdgcn_mfma_f32_16x16x32_bf16(           \
            a[x], b[y], acc[(mb) + x][y], 0, 0, 0);                           \
    __builtin_amdgcn_s_setprio(0);                                            \
  } while (0)

#define BARSYNC()                                                             \
  do {                                                                        \
    __builtin_amdgcn_s_barrier();                                             \
    __builtin_amdgcn_sched_barrier(0);                                        \
  } while (0)

  // prologue: tile0 all slots (8 loads), tile1 B0/A0/B1 (6 loads);
  // vmcnt(6) -> tile0 landed (tile1's 6 may fly, enforced by end-p4 wait).
  STG(2, gB, 0);
  STG(0, gA, 0);
  STG(3, gB, 32);
  STG(1, gA, 32);
  STG(6, gB, 64);
  STG(4, gA, 64);
  STG(7, gB, 96);
  asm volatile("s_waitcnt vmcnt(6)" ::: "memory");
  BARSYNC();

  // iterations 0..6 (steady state); iter i computes K-tiles 2i (buf0), 2i+1
  // (buf1) and stages tiles 2i+2 (buf0 slots) / 2i+3 (buf1 slots).
#pragma unroll 1
  for (int i = 0; i < 7; ++i) {
    const int kc1 = i * 128 + 96;   // tile 2i+1, kk1 (completes buf1)
    const int kc2 = i * 128 + 128;  // tile 2i+2 k-base
    const int kc3 = i * 128 + 192;  // tile 2i+3 k-base
    // p1
    LDA4(0, 0);
    LDB4(2);
    STG(5, gA, kc1);
    BARSYNC();
    MMA16(0);
    BARSYNC();
    // p2
    LDA4(0, 4);
    STG(2, gB, kc2);
    BARSYNC();
    MMA16(4);
    BARSYNC();
    // p3
    LDA4(1, 0);
    LDB4(3);
    STG(0, gA, kc2);
    BARSYNC();
    MMA16(0);
    BARSYNC();
    // p4
    LDA4(1, 4);
    STG(3, gB, kc2 + 32);
    BARSYNC();
    MMA16(4);
    asm volatile("s_waitcnt vmcnt(6)" ::: "memory");
    BARSYNC();
    // p5
    LDA4(4, 0);
    LDB4(6);
    STG(1, gA, kc2 + 32);
    BARSYNC();
    MMA16(0);
    BARSYNC();
    // p6
    LDA4(4, 4);
    STG(6, gB, kc3);
    BARSYNC();
    MMA16(4);
    BARSYNC();
    // p7
    LDA4(5, 0);
    LDB4(7);
    STG(4, gA, kc3);
    BARSYNC();
    MMA16(0);
    BARSYNC();
    // p8
    LDA4(5, 4);
    STG(7, gB, kc3 + 32);
    BARSYNC();
    MMA16(4);
    asm volatile("s_waitcnt vmcnt(6)" ::: "memory");
    BARSYNC();
  }
  // final iteration (i=7): only the p1 stage (tile 15 A-kk1) remains valid;
  // skipped stages break the vmcnt count -> conservative vmcnt(0) at p4.
  {
    LDA4(0, 0);
    LDB4(2);
    STG(5, gA, 7 * 128 + 96);
    BARSYNC();
    MMA16(0);
    BARSYNC();
    LDA4(0, 4);
    BARSYNC();
    MMA16(4);
    BARSYNC();
    LDA4(1, 0);
    LDB4(3);
    BARSYNC();
    MMA16(0);
    BARSYNC();
    LDA4(1, 4);
    BARSYNC();
    MMA16(4);
    asm volatile("s_waitcnt vmcnt(0)" ::: "memory");
    BARSYNC();
    LDA4(4, 0);
    LDB4(6);
    BARSYNC();
    MMA16(0);
    BARSYNC();
    LDA4(4, 4);
    BARSYNC();
    MMA16(4);
    BARSYNC();
    LDA4(5, 0);
    LDB4(7);
    BARSYNC();
    MMA16(0);
    BARSYNC();
    LDA4(5, 4);
    BARSYNC();
    MMA16(4);
  }
#undef STG
#undef LDA4
#undef LDB4
#undef MMA16
#undef BARSYNC

  const int which = bx >> 2;  // 0:Q  1:K  2:V
  if (which < 2) {
    // epilogue: scatter to Qh/Kh head layout (verified R17)
#pragma unroll
    for (int mi = 0; mi < 8; ++mi)
#pragma unroll
      for (int nj = 0; nj < 4; ++nj)
#pragma unroll
        for (int r = 0; r < 4; ++r) {
          int m = (int)m0 + wm + mi * 16 + quad * 4 + r;
          int n = (int)n0 + wn + nj * 16 + lanelo;
          float v = acc[mi][nj][r];
          int t = m >> 3, bb = m & 7;
          int e = n & 1023, h = e >> 6, d = e & 63;
          long off = ((long)(bb * 16 + h)) << 16;
          if (which == 0)
            Qh[off + t * 64 + d] = f2bf(v * QSCALE);
          else
            Kh[off + t * 64 + d] = f2bf(v);
        }
  } else {
    // V epilogue: 4 quarters of 64 n-cols. Per quarter: the 2 owning waves
    // (wid&3==qn; wm 0/128) write a [256][72] transpose tile, then wave=b
    // lane=d threads emit 64B-contiguous stores into Vt[bh][d][1024].
    unsigned short* Vt_s = smem;  // [256][72] = 36864 B (smem free post-loop)
    const long t0g = m0 >> 3;     // multiple of 32
    const int bb = wid;           // 8 waves = 8 batch slots
    const int d = lane;
#pragma unroll
    for (int qn = 0; qn < 4; ++qn) {
      __syncthreads();
      if ((wid & 3) == qn) {
#pragma unroll
        for (int mi = 0; mi < 8; ++mi)
#pragma unroll
          for (int nj = 0; nj < 4; ++nj)
#pragma unroll
            for (int r = 0; r < 4; ++r)
              Vt_s[(wm + mi * 16 + quad * 4 + r) * 72 + nj * 16 + lanelo] =
                  f2bf(acc[mi][nj][r]);
      }
      __syncthreads();
      const int h = (int)(((n0 + qn * 64) & 1023) >> 6);
      long off = ((long)(bb * 16 + h)) << 16;
      __attribute__((aligned(16))) unsigned short vals[32];
#pragma unroll
      for (int t = 0; t < 32; ++t) vals[t] = Vt_s[(t * 8 + bb) * 72 + d];
      uint4* dst = (uint4*)(Vt + off + (long)d * 1024 + t0g);
      dst[0] = ((const uint4*)vals)[0];
      dst[1] = ((const uint4*)vals)[1];
      dst[2] = ((const uint4*)vals)[2];
      dst[3] = ((const uint4*)vals)[3];
    }
  }
}

// ---------------- 128x128 bf16 GEMM mainloop, BK=64, XOR-swizzled (R13) ----
static __device__ __forceinline__ void gemm_tile_128x128(
    const unsigned short* __restrict__ A, const unsigned short* __restrict__ Bt,
    int K, long m0, long n0,
    unsigned short* As, unsigned short* Bs, f32x4 acc[4][4]) {
  const int tid = threadIdx.x;
  const int wid = tid >> 6;
  const int lane = tid & 63;
  const int lanelo = lane & 15;
  const int quad = lane >> 4;
  const int wm = (wid >> 1) << 6;
  const int wn = (wid & 1) << 6;
  const int srow = tid >> 3;                               // 0..31
  const int scol = (((tid & 7) ^ (srow & 7)) << 3);        // pre-swizzled src col

  for (int k0 = 0; k0 < K; k0 += 64) {
    __syncthreads();
    {
      char* la = (char*)As + (wid << 10);
      char* lb = (char*)Bs + (wid << 10);
#pragma unroll
      for (int c = 0; c < 4; ++c) {
        const unsigned short* ga = A + (m0 + srow + c * 32) * K + k0 + scol;
        const unsigned short* gb = Bt + (n0 + srow + c * 32) * K + k0 + scol;
        async_cp16(ga, la + c * 4096);
        async_cp16(gb, lb + c * 4096);
      }
    }
    __syncthreads();
#pragma unroll
    for (int kk = 0; kk < 2; ++kk) {
      bf16x8 a[4], b[4];
#pragma unroll
      for (int i = 0; i < 4; ++i) {
        const int ra = wm + i * 16 + lanelo;
        const int rb = wn + i * 16 + lanelo;
        a[i] = *(const bf16x8*)(As + ra * 64 + (((kk * 4 + quad) ^ (ra & 7)) << 3));
        b[i] = *(const bf16x8*)(Bs + rb * 64 + (((kk * 4 + quad) ^ (rb & 7)) << 3));
      }
#pragma unroll
      for (int i = 0; i < 4; ++i)
#pragma unroll
        for (int j = 0; j < 4; ++j)
          acc[i][j] = __builtin_amdgcn_mfma_f32_16x16x32_bf16(a[i], b[j], acc[i][j], 0, 0, 0);
    }
  }
}

// ---------------- flash attention (log2-domain, 512 thr / 16 rows per wave)
// grid: (128 bh, 8 t-tiles) — same-bh blocks share flat%8 -> same XCD L2.
// R8/R12 version verbatim (best measured: 119.6-127us band). DO NOT PERTURB.
__global__ __launch_bounds__(512, 4) void k_attn(
    const unsigned short* __restrict__ Qh, const unsigned short* __restrict__ Kh,
    const unsigned short* __restrict__ Vt, const unsigned short* __restrict__ B2,
    const float* __restrict__ Mfg, unsigned short* __restrict__ A2) {
  __shared__ unsigned short Ks[128 * 72];  // [s_loc][64+8 pad]   18432 B
  __shared__ unsigned short Vs[64 * 136];  // [d][128+8 pad]      17408 B
  __shared__ unsigned short Ps[128 * 72];  // [t_loc][64+8 pad]   18432 B

  const int tid = threadIdx.x;
  const int wid = tid >> 6;        // 0..7
  const int lane = tid & 63;
  const int lanelo = lane & 15;
  const int quad = lane >> 4;
  const int bh = blockIdx.x;
  const int b = bh >> 4, h = bh & 15;
  const int tt = blockIdx.y;
  const int t0 = tt * 128;
  const long head = (long)bh << 16;

  // Q fragments straight from global (pre-scaled by 0.125*LOG2E): 16 rows/wave
  bf16x8 aq[2];
#pragma unroll
  for (int ks = 0; ks < 2; ++ks)
    aq[ks] = *(const bf16x8*)(Qh + head +
                              (long)(t0 + wid * 16 + lanelo) * 64 +
                              ks * 32 + quad * 8);

  const f32x4 z4 = {0.f, 0.f, 0.f, 0.f};
  f32x4 Oacc[4];
#pragma unroll
  for (int dj = 0; dj < 4; ++dj) Oacc[dj] = z4;
  float mrow[4], lrow[4];
#pragma unroll
  for (int r = 0; r < 4; ++r) { mrow[r] = -1e30f; lrow[r] = 0.f; }

  // bias fragment base: B2 laid out for 256-thr blocks with 2 mi-frags/thread;
  // wave pair (wid>>1) = old wid, (wid&1) = old mi.
  const long biasbase = (((long)(h * 8 + tt) * 8) * 256 + (wid >> 1) * 64 + lane) * 64 +
                        (wid & 1) * 32;

  for (int s0 = 0; s0 < 1024; s0 += 128) {
    // bias + mask loads: independent, issued before barriers for overlap
    bf16x8 bfr[4];
    {
      const bf16x8* bp8 = (const bf16x8*)(B2 + biasbase + ((long)(s0 >> 7) * 256 << 6));
#pragma unroll
      for (int i = 0; i < 4; ++i) bfr[i] = bp8[i];
    }
    float madd[8];
#pragma unroll
    for (int nj = 0; nj < 8; ++nj)
      madd[nj] = Mfg[(long)b * 1024 + s0 + nj * 16 + lanelo];

    __syncthreads();  // all waves done reading prev Ks/Vs
    // stage K tile: 128 x 64 (512 threads x 2 x uint4)
#pragma unroll
    for (int c = 0; c < 2; ++c) {
      int flat = c * 4096 + tid * 8;
      int row = flat >> 6, col = flat & 63;
      uint4 v = *(const uint4*)(Kh + head + (long)(s0 + row) * 64 + col);
      *(uint4*)&Ks[row * 72 + col] = v;
    }
    // stage V tile: 64 x 128 from Vt [d][1024]
#pragma unroll
    for (int c = 0; c < 2; ++c) {
      int flat = c * 4096 + tid * 8;
      int row = flat >> 7, col = flat & 127;
      uint4 v = *(const uint4*)(Vt + head + (long)row * 1024 + s0 + col);
      *(uint4*)&Vs[row * 136 + col] = v;
    }
    __syncthreads();

    // S init = bias + mask (log2 domain), folded into MFMA C-operand:
    // masked columns start at ~-1e30 and underflow to 0 in exp2.
    f32x4 S[8];
#pragma unroll
    for (int nj = 0; nj < 8; ++nj)
#pragma unroll
      for (int r = 0; r < 4; ++r)
        S[nj][r] = (float)bfr[nj >> 1][(nj & 1) * 4 + r] + madd[nj];

    // S += Q K^T (log2 domain)
#pragma unroll
    for (int ks = 0; ks < 2; ++ks) {
      bf16x8 bk[8];
#pragma unroll
      for (int nj = 0; nj < 8; ++nj)
        bk[nj] = *(const bf16x8*)(Ks + (nj * 16 + lanelo) * 72 + ks * 32 + quad * 8);
#pragma unroll
      for (int nj = 0; nj < 8; ++nj)
        S[nj] = __builtin_amdgcn_mfma_f32_16x16x32_bf16(aq[ks], bk[nj], S[nj], 0, 0, 0);
    }

    // online softmax per row (log2 domain; masked entries underflow to 0)
#pragma unroll
    for (int r = 0; r < 4; ++r) {
      float mx = S[0][r];
#pragma unroll
      for (int nj = 1; nj < 8; ++nj) mx = fmaxf(mx, S[nj][r]);
      mx = fmaxf(mx, __shfl_xor(mx, 1, 16));
      mx = fmaxf(mx, __shfl_xor(mx, 2, 16));
      mx = fmaxf(mx, __shfl_xor(mx, 4, 16));
      mx = fmaxf(mx, __shfl_xor(mx, 8, 16));
      float mold = mrow[r];
      float mnew = fmaxf(mold, mx);
      float al = exp2f(mold - mnew);
      mrow[r] = mnew;
      float rs = 0.f;
#pragma unroll
      for (int nj = 0; nj < 8; ++nj) {
        float p = exp2f(S[nj][r] - mnew);
        S[nj][r] = p;
        rs += p;
      }
      rs += __shfl_xor(rs, 1, 16);
      rs += __shfl_xor(rs, 2, 16);
      rs += __shfl_xor(rs, 4, 16);
      rs += __shfl_xor(rs, 8, 16);
      lrow[r] = lrow[r] * al + rs;
#pragma unroll
      for (int dj = 0; dj < 4; ++dj) Oacc[dj][r] *= al;
    }

    // O += P V, in two 64-col halves (P rows are wave-private: no barrier)
#pragma unroll
    for (int half = 0; half < 2; ++half) {
#pragma unroll
      for (int njl = 0; njl < 4; ++njl)
#pragma unroll
        for (int r = 0; r < 4; ++r)
          Ps[(wid * 16 + quad * 4 + r) * 72 + njl * 16 + lanelo] =
              f2bf(S[half * 4 + njl][r]);
#pragma unroll
      for (int ks2 = 0; ks2 < 2; ++ks2) {
        const int ks = half * 2 + ks2;
        bf16x8 ap, bv[4];
        ap = *(const bf16x8*)(Ps + (wid * 16 + lanelo) * 72 + ks2 * 32 + quad * 8);
#pragma unroll
        for (int dj = 0; dj < 4; ++dj)
          bv[dj] = *(const bf16x8*)(Vs + (dj * 16 + lanelo) * 136 + ks * 32 + quad * 8);
#pragma unroll
        for (int dj = 0; dj < 4; ++dj)
          Oacc[dj] = __builtin_amdgcn_mfma_f32_16x16x32_bf16(ap, bv[dj], Oacc[dj], 0, 0, 0);
      }
    }
  }

  // epilogue: A2[(t*8+b)*1024 + h*64 + d] = O / l
#pragma unroll
  for (int r = 0; r < 4; ++r) {
    float rinv = __builtin_amdgcn_rcpf(lrow[r]);
    int t = t0 + wid * 16 + quad * 4 + r;
#pragma unroll
    for (int dj = 0; dj < 4; ++dj) {
      int d = dj * 16 + lanelo;
      A2[(long)(t * 8 + b) * 1024 + h * 64 + d] = f2bf(Oacc[dj][r] * rinv);
    }
  }
}

// ---------------- out projection GEMM -> fp32 d_out (R13 structure) --------
// XCD swizzle: 512 blocks, chunk 64/XCD -> 2MB A2-panel + 2MB WoT per L2.
__global__ __launch_bounds__(256, 2) void k_gemm_out(
    const unsigned short* __restrict__ A, const unsigned short* __restrict__ Bt,
    float* __restrict__ out) {
  __shared__ unsigned short As[128 * 64];
  __shared__ unsigned short Bs[128 * 64];
  f32x4 acc[4][4];
  const f32x4 z4 = {0.f, 0.f, 0.f, 0.f};
#pragma unroll
  for (int i = 0; i < 4; ++i)
#pragma unroll
    for (int j = 0; j < 4; ++j) acc[i][j] = z4;

  const int flat = blockIdx.y * 8 + blockIdx.x;
  const int swz = (flat & 7) * 64 + (flat >> 3);  // bijective (512%8==0)
  const long m0 = (long)(swz / 8) * 128;
  const long n0 = (long)(swz % 8) * 128;
  gemm_tile_128x128(A, Bt, 1024, m0, n0, As, Bs, acc);

  const int tid = threadIdx.x;
  const int wid = tid >> 6;
  const int lane = tid & 63;
  const int lanelo = lane & 15;
  const int quad = lane >> 4;
  const int wm = (wid >> 1) << 6;
  const int wn = (wid & 1) << 6;
#pragma unroll
  for (int mi = 0; mi < 4; ++mi)
#pragma unroll
    for (int nj = 0; nj < 4; ++nj)
#pragma unroll
      for (int r = 0; r < 4; ++r) {
        long m = m0 + wm + mi * 16 + quad * 4 + r;
        long n = n0 + wn + nj * 16 + lanelo;
        out[m * 1024 + n] = acc[mi][nj][r];
      }
}

// ---------------- launch ----------------
extern "C" void kernel_launch(void* const* d_in, const int* in_sizes, int n_in,
                              void* d_out, int out_size, void* d_ws, size_t ws_size,
                              hipStream_t stream) {
  const float* query = (const float*)d_in[0];
  const int* mask = (const int*)d_in[1];
  const float* bias = (const float*)d_in[2];
  const float* wq = (const float*)d_in[3];
  const float* wk = (const float*)d_in[4];
  const float* wv = (const float*)d_in[5];
  const float* wo = (const float*)d_in[6];
  float* out = (float*)d_out;

  char* ws = (char*)d_ws;
  const size_t MB = 1024 * 1024;
  unsigned short* Abuf  = (unsigned short*)(ws);             // 16 MB
  unsigned short* WqkvT = (unsigned short*)(ws + 16 * MB);   // 6 MB
  unsigned short* WoT   = (unsigned short*)(ws + 22 * MB);   // 2 MB
  unsigned short* Qh    = (unsigned short*)(ws + 24 * MB);   // 16 MB
  unsigned short* Kh    = (unsigned short*)(ws + 40 * MB);   // 16 MB
  unsigned short* Vt    = (unsigned short*)(ws + 56 * MB);   // 16 MB
  unsigned short* A2    = (unsigned short*)(ws + 72 * MB);   // 16 MB
  unsigned short* B2    = (unsigned short*)(ws + 88 * MB);   // 32 MB
  float*          Mfg   = (float*)(ws + 120 * MB);           // 32 KB

  k_prep<<<dim3(13344), dim3(256), 0, stream>>>(query, mask, bias, wq, wk, wv, wo,
                                                Abuf, Mfg, WqkvT, WoT, B2);
  k_gemm_qkv<<<dim3(12, 32), dim3(512), 0, stream>>>(Abuf, WqkvT, Qh, Kh, Vt);
  k_attn<<<dim3(128, 8), dim3(512), 0, stream>>>(Qh, Kh, Vt, B2, Mfg, A2);
  k_gemm_out<<<dim3(8, 64), dim3(256), 0, stream>>>(A2, WoT, out);
}

// Round 14
// 349.455 us; speedup vs baseline: 1.0271x; 1.0271x over previous
//
#include <hip/hip_runtime.h>

// ---------------------------------------------------------------------------
// MultiheadAttention: T=1024, B=8, E=1024, H=16, HD=64, SCALE=0.125
// R19: restore R17 (measured best, 350.5us). R18's V-fusion tail (384 blocks
//     at 1/CU = 1.5 rounds, tail at 50% util for a full block-duration)
//     regressed -8us -> split qk(256=1 round)/v(512@2/CU) is the better
//     schedule. One bounded tweak: k_gemm_v / k_gemm_out occupancy 2->3
//     blocks/CU via __launch_bounds__(256,3) (reg est ~130 < 170 cap;
//     R16 showed 2-phase loops are covered by INTER-block overlap, which
//     more resident blocks strengthens). k_attn/k_prep/k_gemm_qk identical.
// ---------------------------------------------------------------------------

typedef __bf16 bf16x8 __attribute__((ext_vector_type(8)));
typedef float f32x4 __attribute__((ext_vector_type(4)));

#define LOG2E 1.4426950408889634f
#define QSCALE 0.18033688011112042f  // 0.125 * LOG2E

// round-to-nearest-even (one-time prep kernels)
static __device__ __forceinline__ unsigned short f2bf_rn(float f) {
  union { float f; unsigned u; } x;
  x.f = f;
  unsigned r = (x.u + 0x7fffu + ((x.u >> 16) & 1u)) >> 16;
  return (unsigned short)r;
}
// round-half-up (hot paths: 2 VALU ops)
static __device__ __forceinline__ unsigned short f2bf(float f) {
  union { float f; unsigned u; } x;
  x.f = f;
  return (unsigned short)((x.u + 0x8000u) >> 16);
}

static __device__ __forceinline__ void async_cp16(const void* g, void* l) {
  __builtin_amdgcn_global_load_lds((__attribute__((address_space(1))) void*)g,
                                   (__attribute__((address_space(3))) void*)l,
                                   16, 0, 0);
}

// ---------------- fused prep: biasT | transw4 | cvt | mask ----------------
// grid: [0,1024) biasT  [1024,5120) transw4  [5120,13312) cvt  [13312,13344) mask
__global__ __launch_bounds__(256, 2) void k_prep(
    const float* __restrict__ query, const int* __restrict__ mask,
    const float* __restrict__ bias,
    const float* __restrict__ wq, const float* __restrict__ wk,
    const float* __restrict__ wv, const float* __restrict__ wo,
    unsigned short* __restrict__ Abuf, float* __restrict__ Mfg,
    unsigned short* __restrict__ WqkvT, unsigned short* __restrict__ WoT,
    unsigned short* __restrict__ B2) {
  __shared__ char shraw[128 * 132 * 2];  // 33792 B (biasT tile; transw reuses)
  const int bid = blockIdx.x;
  const int tid = threadIdx.x;

  if (bid < 1024) {
    // ---- biasT: fragment-layout bf16, log2 domain ----
    unsigned short* tile = (unsigned short*)shraw;
    const int ss = bid & 7, tt = (bid >> 3) & 7, h = bid >> 6;
    const float* src = bias + ((long)h * 1024 + tt * 128) * 1024 + ss * 128;
#pragma unroll
    for (int c = 0; c < 16; ++c) {
      int flat = c * 256 + tid;
      int row = flat >> 5, col = (flat & 31) << 2;
      float4 v = *(const float4*)(src + (long)row * 1024 + col);
      unsigned short* t4 = &tile[row * 132 + col];
      t4[0] = f2bf_rn(v.x * LOG2E); t4[1] = f2bf_rn(v.y * LOG2E);
      t4[2] = f2bf_rn(v.z * LOG2E); t4[3] = f2bf_rn(v.w * LOG2E);
    }
    __syncthreads();
    const int wid = tid >> 6, lane = tid & 63, lanelo = lane & 15, quad = lane >> 4;
    unsigned short outv[64];
#pragma unroll
    for (int mi = 0; mi < 2; ++mi)
#pragma unroll
      for (int nj = 0; nj < 8; ++nj)
#pragma unroll
        for (int r = 0; r < 4; ++r)
          outv[mi * 32 + nj * 4 + r] =
              tile[(wid * 32 + mi * 16 + quad * 4 + r) * 132 + nj * 16 + lanelo];
    unsigned short* dst = B2 + ((((long)(h * 8 + tt) * 8 + ss) * 256 + tid) << 6);
#pragma unroll
    for (int i = 0; i < 8; ++i) ((uint4*)dst)[i] = ((const uint4*)outv)[i];
  } else if (bid < 5120) {
    // ---- transw4: dst[e][d] = f2bf(src[d][e]) ----
    float (*tile)[33] = (float(*)[33])shraw;
    const int f = bid - 1024;
    const int bx = (f & 31) << 5;
    const int by = ((f >> 5) & 31) << 5;
    const int z = f >> 10;
    const float* src = (z == 0) ? wq : (z == 1) ? wk : (z == 2) ? wv : wo;
    unsigned short* dst = (z < 3) ? WqkvT + (size_t)z * 1024 * 1024 : WoT;
    const int tx = tid & 31, ty = tid >> 5;
#pragma unroll
    for (int i = 0; i < 32; i += 8)
      tile[ty + i][tx] = src[(size_t)(by + ty + i) * 1024 + bx + tx];
    __syncthreads();
#pragma unroll
    for (int i = 0; i < 32; i += 8)
      dst[(size_t)(bx + ty + i) * 1024 + by + tx] = f2bf_rn(tile[tx][ty + i]);
  } else if (bid < 13312) {
    // ---- cvt: query fp32 -> bf16 ----
    const int idx = (bid - 5120) * 256 + tid;
    const float4 f = ((const float4*)query)[idx];
    unsigned lo = (unsigned)f2bf_rn(f.x) | ((unsigned)f2bf_rn(f.y) << 16);
    unsigned hi = (unsigned)f2bf_rn(f.z) | ((unsigned)f2bf_rn(f.w) << 16);
    uint2 v; v.x = lo; v.y = hi;
    *(uint2*)(Abuf + (size_t)idx * 4) = v;
  } else {
    // ---- mask -> additive float ----
    const int i = (bid - 13312) * 256 + tid;  // 8192 total
    Mfg[i] = mask[i] ? -1e30f : 0.f;
  }
}

// ======================= 8-phase 256x256 Q/K GEMM ==========================
// C[0:8192, 0:2048] of Abuf x WqkvT^T, scattered to Qh/Kh head layout.
// LDS slots (16KB = 8192 shorts each): per buffer q (=tile%2):
//   A-kk0 = q*4+0, A-kk1 = q*4+1, B-kk0 = q*4+2, B-kk1 = q*4+3.
// Slot layout: lds_line (64 shorts) = 2 source rows; 16B chunk at pos
//   ((row&1)*4 + c) ^ (lds_line&7), c = k-chunk (8 shorts) within kk-half.
__global__ __launch_bounds__(512, 2) void k_gemm_qk(
    const unsigned short* __restrict__ A, const unsigned short* __restrict__ Bt,
    unsigned short* __restrict__ Qh, unsigned short* __restrict__ Kh) {
  __shared__ unsigned short smem[65536];  // 128 KB

  const int tid = threadIdx.x;
  const int wid = tid >> 6;
  const int lane = tid & 63;
  const int lanelo = lane & 15;
  const int quad = lane >> 4;
  const int wm = (wid >> 2) << 7;  // 0 / 128
  const int wn = (wid & 3) << 6;   // 0 / 64 / 128 / 192
  const int K = 1024;

  // XCD swizzle: grid (8,32) = 256 blocks, chunk 32/XCD -> 4 m-panels per L2
  const int flat = blockIdx.y * 8 + blockIdx.x;
  const int swz = (flat & 7) * 32 + (flat >> 3);
  const int bx = swz & 7, by = swz >> 3;
  const long m0 = (long)by * 256;
  const long n0 = (long)bx * 256;

  // staging geometry: thread stages 16B chunks L = tid (rows 0-127 half)
  // and L = tid+512 (rows 128-255). Inverse of the LDS interleave:
  const int x_ = (tid & 7) ^ ((tid >> 3) & 7);
  const int row_s = ((tid >> 3) << 1) + (x_ >> 2);
  const int col_s = (x_ & 3) << 3;
  const unsigned short* gA = A + (m0 + row_s) * K + col_s;
  const unsigned short* gB = Bt + (n0 + row_s) * K + col_s;

#define STG(slot, gp, kc)                                        \
  do {                                                           \
    const unsigned short* _g = (gp) + (kc);                      \
    char* _l = (char*)smem + ((slot) << 14) + (wid << 10);       \
    async_cp16(_g, _l);                                          \
    async_cp16(_g + 128 * 1024, _l + 8192);                      \
  } while (0)

  // ds_read offsets (shorts): line = base_line + 8*frag; pos per-lane const
  const int lhalf = lanelo >> 1;
  const int posa = ((((lanelo & 1) << 2) + quad) ^ lhalf) << 3;
  const int aoff = ((wm >> 1) + lhalf) * 64 + posa;
  const int boff = ((wn >> 1) + lhalf) * 64 + posa;

  bf16x8 a[4], b[4];
#define LDA4(slot, mb)                                                        \
  do {                                                                        \
    a[0] = *(const bf16x8*)(smem + (slot) * 8192 + aoff + ((mb) + 0) * 512);  \
    a[1] = *(const bf16x8*)(smem + (slot) * 8192 + aoff + ((mb) + 1) * 512);  \
    a[2] = *(const bf16x8*)(smem + (slot) * 8192 + aoff + ((mb) + 2) * 512);  \
    a[3] = *(const bf16x8*)(smem + (slot) * 8192 + aoff + ((mb) + 3) * 512);  \
  } while (0)
#define LDB4(slot)                                                            \
  do {                                                                        \
    b[0] = *(const bf16x8*)(smem + (slot) * 8192 + boff + 0 * 512);           \
    b[1] = *(const bf16x8*)(smem + (slot) * 8192 + boff + 1 * 512);           \
    b[2] = *(const bf16x8*)(smem + (slot) * 8192 + boff + 2 * 512);           \
    b[3] = *(const bf16x8*)(smem + (slot) * 8192 + boff + 3 * 512);           \
  } while (0)

  f32x4 acc[8][4];
  const f32x4 z4 = {0.f, 0.f, 0.f, 0.f};
#pragma unroll
  for (int i = 0; i < 8; ++i)
#pragma unroll
    for (int j = 0; j < 4; ++j) acc[i][j] = z4;

#define MMA16(mb)                                                             \
  do {                                                                        \
    __builtin_amdgcn_s_setprio(1);                                            \
    _Pragma("unroll") for (int x = 0; x < 4; ++x)                             \
        _Pragma("unroll") for (int y = 0; y < 4; ++y)                         \
        acc[(mb) + x][y] = __builtin_amdgcn_mfma_f32_16x16x32_bf16(           \
            a[x], b[y], acc[(mb) + x][y], 0, 0, 0);                           \
    __builtin_amdgcn_s_setprio(0);                                            \
  } while (0)

#define BARSYNC()                                                             \
  do {                                                                        \
    __builtin_amdgcn_s_barrier();                                             \
    __builtin_amdgcn_sched_barrier(0);                                        \
  } while (0)

  // prologue: tile0 all slots (8 loads), tile1 B0/A0/B1 (6 loads);
  // vmcnt(6) -> tile0 landed (tile1's 6 may fly, enforced by end-p4 wait).
  STG(2, gB, 0);
  STG(0, gA, 0);
  STG(3, gB, 32);
  STG(1, gA, 32);
  STG(6, gB, 64);
  STG(4, gA, 64);
  STG(7, gB, 96);
  asm volatile("s_waitcnt vmcnt(6)" ::: "memory");
  BARSYNC();

  // iterations 0..6 (steady state); iter i computes K-tiles 2i (buf0), 2i+1
  // (buf1) and stages tiles 2i+2 (buf0 slots) / 2i+3 (buf1 slots).
#pragma unroll 1
  for (int i = 0; i < 7; ++i) {
    const int kc1 = i * 128 + 96;   // tile 2i+1, kk1 (completes buf1)
    const int kc2 = i * 128 + 128;  // tile 2i+2 k-base
    const int kc3 = i * 128 + 192;  // tile 2i+3 k-base
    // p1
    LDA4(0, 0);
    LDB4(2);
    STG(5, gA, kc1);
    BARSYNC();
    MMA16(0);
    BARSYNC();
    // p2
    LDA4(0, 4);
    STG(2, gB, kc2);
    BARSYNC();
    MMA16(4);
    BARSYNC();
    // p3
    LDA4(1, 0);
    LDB4(3);
    STG(0, gA, kc2);
    BARSYNC();
    MMA16(0);
    BARSYNC();
    // p4
    LDA4(1, 4);
    STG(3, gB, kc2 + 32);
    BARSYNC();
    MMA16(4);
    asm volatile("s_waitcnt vmcnt(6)" ::: "memory");
    BARSYNC();
    // p5
    LDA4(4, 0);
    LDB4(6);
    STG(1, gA, kc2 + 32);
    BARSYNC();
    MMA16(0);
    BARSYNC();
    // p6
    LDA4(4, 4);
    STG(6, gB, kc3);
    BARSYNC();
    MMA16(4);
    BARSYNC();
    // p7
    LDA4(5, 0);
    LDB4(7);
    STG(4, gA, kc3);
    BARSYNC();
    MMA16(0);
    BARSYNC();
    // p8
    LDA4(5, 4);
    STG(7, gB, kc3 + 32);
    BARSYNC();
    MMA16(4);
    asm volatile("s_waitcnt vmcnt(6)" ::: "memory");
    BARSYNC();
  }
  // final iteration (i=7): only the p1 stage (tile 15 A-kk1) remains valid;
  // skipped stages break the vmcnt count -> conservative vmcnt(0) at p4.
  {
    LDA4(0, 0);
    LDB4(2);
    STG(5, gA, 7 * 128 + 96);
    BARSYNC();
    MMA16(0);
    BARSYNC();
    LDA4(0, 4);
    BARSYNC();
    MMA16(4);
    BARSYNC();
    LDA4(1, 0);
    LDB4(3);
    BARSYNC();
    MMA16(0);
    BARSYNC();
    LDA4(1, 4);
    BARSYNC();
    MMA16(4);
    asm volatile("s_waitcnt vmcnt(0)" ::: "memory");
    BARSYNC();
    LDA4(4, 0);
    LDB4(6);
    BARSYNC();
    MMA16(0);
    BARSYNC();
    LDA4(4, 4);
    BARSYNC();
    MMA16(4);
    BARSYNC();
    LDA4(5, 0);
    LDB4(7);
    BARSYNC();
    MMA16(0);
    BARSYNC();
    LDA4(5, 4);
    BARSYNC();
    MMA16(4);
  }
#undef STG
#undef LDA4
#undef LDB4
#undef MMA16
#undef BARSYNC

  // epilogue: scatter to Qh/Kh head layout (same formula as 128^2 version)
  const int which = bx >> 2;  // 0:Q (n 0-1023)  1:K (n 1024-2047)
#pragma unroll
  for (int mi = 0; mi < 8; ++mi)
#pragma unroll
    for (int nj = 0; nj < 4; ++nj)
#pragma unroll
      for (int r = 0; r < 4; ++r) {
        int m = (int)m0 + wm + mi * 16 + quad * 4 + r;
        int n = (int)n0 + wn + nj * 16 + lanelo;
        float v = acc[mi][nj][r];
        int t = m >> 3, bb = m & 7;
        int e = n & 1023, h = e >> 6, d = e & 63;
        long off = ((long)(bb * 16 + h)) << 16;
        if (which == 0)
          Qh[off + t * 64 + d] = f2bf(v * QSCALE);
        else
          Kh[off + t * 64 + d] = f2bf(v);
      }
}

// ---------------- 128x128 bf16 GEMM mainloop, BK=64, XOR-swizzled (R13) ----
static __device__ __forceinline__ void gemm_tile_128x128(
    const unsigned short* __restrict__ A, const unsigned short* __restrict__ Bt,
    int K, long m0, long n0,
    unsigned short* As, unsigned short* Bs, f32x4 acc[4][4]) {
  const int tid = threadIdx.x;
  const int wid = tid >> 6;
  const int lane = tid & 63;
  const int lanelo = lane & 15;
  const int quad = lane >> 4;
  const int wm = (wid >> 1) << 6;
  const int wn = (wid & 1) << 6;
  const int srow = tid >> 3;                               // 0..31
  const int scol = (((tid & 7) ^ (srow & 7)) << 3);        // pre-swizzled src col

  for (int k0 = 0; k0 < K; k0 += 64) {
    __syncthreads();
    {
      char* la = (char*)As + (wid << 10);
      char* lb = (char*)Bs + (wid << 10);
#pragma unroll
      for (int c = 0; c < 4; ++c) {
        const unsigned short* ga = A + (m0 + srow + c * 32) * K + k0 + scol;
        const unsigned short* gb = Bt + (n0 + srow + c * 32) * K + k0 + scol;
        async_cp16(ga, la + c * 4096);
        async_cp16(gb, lb + c * 4096);
      }
    }
    __syncthreads();
#pragma unroll
    for (int kk = 0; kk < 2; ++kk) {
      bf16x8 a[4], b[4];
#pragma unroll
      for (int i = 0; i < 4; ++i) {
        const int ra = wm + i * 16 + lanelo;
        const int rb = wn + i * 16 + lanelo;
        a[i] = *(const bf16x8*)(As + ra * 64 + (((kk * 4 + quad) ^ (ra & 7)) << 3));
        b[i] = *(const bf16x8*)(Bs + rb * 64 + (((kk * 4 + quad) ^ (rb & 7)) << 3));
      }
#pragma unroll
      for (int i = 0; i < 4; ++i)
#pragma unroll
        for (int j = 0; j < 4; ++j)
          acc[i][j] = __builtin_amdgcn_mfma_f32_16x16x32_bf16(a[i], b[j], acc[i][j], 0, 0, 0);
    }
  }
}

// ---------------- V GEMM (128^2 R13 structure, V epilogue only) -------------
// n covers WqkvT rows 2048..3071; output Vt[bh][d][1024]. 3 blocks/CU.
__global__ __launch_bounds__(256, 3) void k_gemm_v(
    const unsigned short* __restrict__ A, const unsigned short* __restrict__ Bt,
    unsigned short* __restrict__ Vt) {
  __shared__ unsigned short smem[16384];  // As(8K shorts) + Bs(8K); epi reuses [128][72]
  unsigned short* As = smem;
  unsigned short* Bs = smem + 8192;
  f32x4 acc[4][4];
  const f32x4 z4 = {0.f, 0.f, 0.f, 0.f};
#pragma unroll
  for (int i = 0; i < 4; ++i)
#pragma unroll
    for (int j = 0; j < 4; ++j) acc[i][j] = z4;

  const int flat = blockIdx.y * 8 + blockIdx.x;     // 512 blocks
  const int swz = (flat & 7) * 64 + (flat >> 3);    // bijective (512%8==0)
  const long m0 = (long)(swz / 8) * 128;
  const long n0 = 2048 + (long)(swz % 8) * 128;
  gemm_tile_128x128(A, Bt, 1024, m0, n0, As, Bs, acc);

  const int tid = threadIdx.x;
  const int wid = tid >> 6;
  const int lane = tid & 63;
  const int lanelo = lane & 15;
  const int quad = lane >> 4;
  const int wm = (wid >> 1) << 6;
  const int wn = (wid & 1) << 6;

  // V epilogue: LDS transpose -> 32B-run coalesced stores into Vt[bh][d][1024]
  unsigned short* Vt_s = smem;  // [128][72]
  const long t0g = m0 >> 3;
#pragma unroll
  for (int half = 0; half < 2; ++half) {
    __syncthreads();
    if ((wid & 1) == half) {
#pragma unroll
      for (int mi = 0; mi < 4; ++mi)
#pragma unroll
        for (int nj = 0; nj < 4; ++nj)
#pragma unroll
          for (int r = 0; r < 4; ++r)
            Vt_s[(wm + mi * 16 + quad * 4 + r) * 72 + nj * 16 + lanelo] =
                f2bf(acc[mi][nj][r]);
    }
    __syncthreads();
    const int h = (((int)(n0 & 1023)) >> 6) + half;
#pragma unroll
    for (int pp = 0; pp < 2; ++pp) {
      int p = tid + pp * 256;
      int b = p >> 6, d = p & 63;
      long off = ((long)(b * 16 + h)) << 16;
      __attribute__((aligned(16))) unsigned short vals[16];
#pragma unroll
      for (int t = 0; t < 16; ++t) vals[t] = Vt_s[(t * 8 + b) * 72 + d];
      uint4* dst = (uint4*)(Vt + off + (long)d * 1024 + t0g);
      dst[0] = ((const uint4*)vals)[0];
      dst[1] = ((const uint4*)vals)[1];
    }
  }
}

// ---------------- flash attention (log2-domain, 512 thr / 16 rows per wave)
// grid: (128 bh, 8 t-tiles) — same-bh blocks share flat%8 -> same XCD L2.
// R8/R12 version verbatim (best measured: 119.6-127us band). DO NOT PERTURB.
__global__ __launch_bounds__(512, 4) void k_attn(
    const unsigned short* __restrict__ Qh, const unsigned short* __restrict__ Kh,
    const unsigned short* __restrict__ Vt, const unsigned short* __restrict__ B2,
    const float* __restrict__ Mfg, unsigned short* __restrict__ A2) {
  __shared__ unsigned short Ks[128 * 72];  // [s_loc][64+8 pad]   18432 B
  __shared__ unsigned short Vs[64 * 136];  // [d][128+8 pad]      17408 B
  __shared__ unsigned short Ps[128 * 72];  // [t_loc][64+8 pad]   18432 B

  const int tid = threadIdx.x;
  const int wid = tid >> 6;        // 0..7
  const int lane = tid & 63;
  const int lanelo = lane & 15;
  const int quad = lane >> 4;
  const int bh = blockIdx.x;
  const int b = bh >> 4, h = bh & 15;
  const int tt = blockIdx.y;
  const int t0 = tt * 128;
  const long head = (long)bh << 16;

  // Q fragments straight from global (pre-scaled by 0.125*LOG2E): 16 rows/wave
  bf16x8 aq[2];
#pragma unroll
  for (int ks = 0; ks < 2; ++ks)
    aq[ks] = *(const bf16x8*)(Qh + head +
                              (long)(t0 + wid * 16 + lanelo) * 64 +
                              ks * 32 + quad * 8);

  const f32x4 z4 = {0.f, 0.f, 0.f, 0.f};
  f32x4 Oacc[4];
#pragma unroll
  for (int dj = 0; dj < 4; ++dj) Oacc[dj] = z4;
  float mrow[4], lrow[4];
#pragma unroll
  for (int r = 0; r < 4; ++r) { mrow[r] = -1e30f; lrow[r] = 0.f; }

  // bias fragment base: B2 laid out for 256-thr blocks with 2 mi-frags/thread;
  // wave pair (wid>>1) = old wid, (wid&1) = old mi.
  const long biasbase = (((long)(h * 8 + tt) * 8) * 256 + (wid >> 1) * 64 + lane) * 64 +
                        (wid & 1) * 32;

  for (int s0 = 0; s0 < 1024; s0 += 128) {
    // bias + mask loads: independent, issued before barriers for overlap
    bf16x8 bfr[4];
    {
      const bf16x8* bp8 = (const bf16x8*)(B2 + biasbase + ((long)(s0 >> 7) * 256 << 6));
#pragma unroll
      for (int i = 0; i < 4; ++i) bfr[i] = bp8[i];
    }
    float madd[8];
#pragma unroll
    for (int nj = 0; nj < 8; ++nj)
      madd[nj] = Mfg[(long)b * 1024 + s0 + nj * 16 + lanelo];

    __syncthreads();  // all waves done reading prev Ks/Vs
    // stage K tile: 128 x 64 (512 threads x 2 x uint4)
#pragma unroll
    for (int c = 0; c < 2; ++c) {
      int flat = c * 4096 + tid * 8;
      int row = flat >> 6, col = flat & 63;
      uint4 v = *(const uint4*)(Kh + head + (long)(s0 + row) * 64 + col);
      *(uint4*)&Ks[row * 72 + col] = v;
    }
    // stage V tile: 64 x 128 from Vt [d][1024]
#pragma unroll
    for (int c = 0; c < 2; ++c) {
      int flat = c * 4096 + tid * 8;
      int row = flat >> 7, col = flat & 127;
      uint4 v = *(const uint4*)(Vt + head + (long)row * 1024 + s0 + col);
      *(uint4*)&Vs[row * 136 + col] = v;
    }
    __syncthreads();

    // S init = bias + mask (log2 domain), folded into MFMA C-operand:
    // masked columns start at ~-1e30 and underflow to 0 in exp2.
    f32x4 S[8];
#pragma unroll
    for (int nj = 0; nj < 8; ++nj)
#pragma unroll
      for (int r = 0; r < 4; ++r)
        S[nj][r] = (float)bfr[nj >> 1][(nj & 1) * 4 + r] + madd[nj];

    // S += Q K^T (log2 domain)
#pragma unroll
    for (int ks = 0; ks < 2; ++ks) {
      bf16x8 bk[8];
#pragma unroll
      for (int nj = 0; nj < 8; ++nj)
        bk[nj] = *(const bf16x8*)(Ks + (nj * 16 + lanelo) * 72 + ks * 32 + quad * 8);
#pragma unroll
      for (int nj = 0; nj < 8; ++nj)
        S[nj] = __builtin_amdgcn_mfma_f32_16x16x32_bf16(aq[ks], bk[nj], S[nj], 0, 0, 0);
    }

    // online softmax per row (log2 domain; masked entries underflow to 0)
#pragma unroll
    for (int r = 0; r < 4; ++r) {
      float mx = S[0][r];
#pragma unroll
      for (int nj = 1; nj < 8; ++nj) mx = fmaxf(mx, S[nj][r]);
      mx = fmaxf(mx, __shfl_xor(mx, 1, 16));
      mx = fmaxf(mx, __shfl_xor(mx, 2, 16));
      mx = fmaxf(mx, __shfl_xor(mx, 4, 16));
      mx = fmaxf(mx, __shfl_xor(mx, 8, 16));
      float mold = mrow[r];
      float mnew = fmaxf(mold, mx);
      float al = exp2f(mold - mnew);
      mrow[r] = mnew;
      float rs = 0.f;
#pragma unroll
      for (int nj = 0; nj < 8; ++nj) {
        float p = exp2f(S[nj][r] - mnew);
        S[nj][r] = p;
        rs += p;
      }
      rs += __shfl_xor(rs, 1, 16);
      rs += __shfl_xor(rs, 2, 16);
      rs += __shfl_xor(rs, 4, 16);
      rs += __shfl_xor(rs, 8, 16);
      lrow[r] = lrow[r] * al + rs;
#pragma unroll
      for (int dj = 0; dj < 4; ++dj) Oacc[dj][r] *= al;
    }

    // O += P V, in two 64-col halves (P rows are wave-private: no barrier)
#pragma unroll
    for (int half = 0; half < 2; ++half) {
#pragma unroll
      for (int njl = 0; njl < 4; ++njl)
#pragma unroll
        for (int r = 0; r < 4; ++r)
          Ps[(wid * 16 + quad * 4 + r) * 72 + njl * 16 + lanelo] =
              f2bf(S[half * 4 + njl][r]);
#pragma unroll
      for (int ks2 = 0; ks2 < 2; ++ks2) {
        const int ks = half * 2 + ks2;
        bf16x8 ap, bv[4];
        ap = *(const bf16x8*)(Ps + (wid * 16 + lanelo) * 72 + ks2 * 32 + quad * 8);
#pragma unroll
        for (int dj = 0; dj < 4; ++dj)
          bv[dj] = *(const bf16x8*)(Vs + (dj * 16 + lanelo) * 136 + ks * 32 + quad * 8);
#pragma unroll
        for (int dj = 0; dj < 4; ++dj)
          Oacc[dj] = __builtin_amdgcn_mfma_f32_16x16x32_bf16(ap, bv[dj], Oacc[dj], 0, 0, 0);
      }
    }
  }

  // epilogue: A2[(t*8+b)*1024 + h*64 + d] = O / l
#pragma unroll
  for (int r = 0; r < 4; ++r) {
    float rinv = __builtin_amdgcn_rcpf(lrow[r]);
    int t = t0 + wid * 16 + quad * 4 + r;
#pragma unroll
    for (int dj = 0; dj < 4; ++dj) {
      int d = dj * 16 + lanelo;
      A2[(long)(t * 8 + b) * 1024 + h * 64 + d] = f2bf(Oacc[dj][r] * rinv);
    }
  }
}

// ---------------- out projection GEMM -> fp32 d_out (R13 structure) --------
// XCD swizzle: 512 blocks, chunk 64/XCD. 3 blocks/CU.
__global__ __launch_bounds__(256, 3) void k_gemm_out(
    const unsigned short* __restrict__ A, const unsigned short* __restrict__ Bt,
    float* __restrict__ out) {
  __shared__ unsigned short As[128 * 64];
  __shared__ unsigned short Bs[128 * 64];
  f32x4 acc[4][4];
  const f32x4 z4 = {0.f, 0.f, 0.f, 0.f};
#pragma unroll
  for (int i = 0; i < 4; ++i)
#pragma unroll
    for (int j = 0; j < 4; ++j) acc[i][j] = z4;

  const int flat = blockIdx.y * 8 + blockIdx.x;
  const int swz = (flat & 7) * 64 + (flat >> 3);  // bijective (512%8==0)
  const long m0 = (long)(swz / 8) * 128;
  const long n0 = (long)(swz % 8) * 128;
  gemm_tile_128x128(A, Bt, 1024, m0, n0, As, Bs, acc);

  const int tid = threadIdx.x;
  const int wid = tid >> 6;
  const int lane = tid & 63;
  const int lanelo = lane & 15;
  const int quad = lane >> 4;
  const int wm = (wid >> 1) << 6;
  const int wn = (wid & 1) << 6;
#pragma unroll
  for (int mi = 0; mi < 4; ++mi)
#pragma unroll
    for (int nj = 0; nj < 4; ++nj)
#pragma unroll
      for (int r = 0; r < 4; ++r) {
        long m = m0 + wm + mi * 16 + quad * 4 + r;
        long n = n0 + wn + nj * 16 + lanelo;
        out[m * 1024 + n] = acc[mi][nj][r];
      }
}

// ---------------- launch ----------------
extern "C" void kernel_launch(void* const* d_in, const int* in_sizes, int n_in,
                              void* d_out, int out_size, void* d_ws, size_t ws_size,
                              hipStream_t stream) {
  const float* query = (const float*)d_in[0];
  const int* mask = (const int*)d_in[1];
  const float* bias = (const float*)d_in[2];
  const float* wq = (const float*)d_in[3];
  const float* wk = (const float*)d_in[4];
  const float* wv = (const float*)d_in[5];
  const float* wo = (const float*)d_in[6];
  float* out = (float*)d_out;

  char* ws = (char*)d_ws;
  const size_t MB = 1024 * 1024;
  unsigned short* Abuf  = (unsigned short*)(ws);             // 16 MB
  unsigned short* WqkvT = (unsigned short*)(ws + 16 * MB);   // 6 MB
  unsigned short* WoT   = (unsigned short*)(ws + 22 * MB);   // 2 MB
  unsigned short* Qh    = (unsigned short*)(ws + 24 * MB);   // 16 MB
  unsigned short* Kh    = (unsigned short*)(ws + 40 * MB);   // 16 MB
  unsigned short* Vt    = (unsigned short*)(ws + 56 * MB);   // 16 MB
  unsigned short* A2    = (unsigned short*)(ws + 72 * MB);   // 16 MB
  unsigned short* B2    = (unsigned short*)(ws + 88 * MB);   // 32 MB
  float*          Mfg   = (float*)(ws + 120 * MB);           // 32 KB

  k_prep<<<dim3(13344), dim3(256), 0, stream>>>(query, mask, bias, wq, wk, wv, wo,
                                                Abuf, Mfg, WqkvT, WoT, B2);
  k_gemm_qk<<<dim3(8, 32), dim3(512), 0, stream>>>(Abuf, WqkvT, Qh, Kh);
  k_gemm_v<<<dim3(8, 64), dim3(256), 0, stream>>>(Abuf, WqkvT, Vt);
  k_attn<<<dim3(128, 8), dim3(512), 0, stream>>>(Qh, Kh, Vt, B2, Mfg, A2);
  k_gemm_out<<<dim3(8, 64), dim3(256), 0, stream>>>(A2, WoT, out);
}